// Round 1
// baseline (468.454 us; speedup 1.0000x reference)
//
#include <hip/hip_runtime.h>
#include <hip/hip_bf16.h>

// TransformerEncoderLayer: B=4,S=4096,D=1024, 8 heads x 128.
// Pipeline:
//   cast x -> bf16; transpose+cast W* -> Wt[n][k] bf16; concat biases
//   GEMM1: qkv = x @ [Wq|Wk|Wv] + b      (fp32 out if ws fits, else bf16)
//   attention: per-token 8x8 softmax     (writes attn_weights to d_out tail)
//   GEMM2: h = relu(out @ W1 + b1)       (bf16 out)
//   GEMM3: ff = h @ W2 + b2              (fp32 -> d_out head)

#define DI __device__ __forceinline__

typedef __bf16 bf16raw;
typedef bf16raw bf16x8 __attribute__((ext_vector_type(8)));
typedef float floatx4 __attribute__((ext_vector_type(4)));

DI unsigned short f2bf(float f) {
    __hip_bfloat16 h = __float2bfloat16(f);  // RNE
    return *reinterpret_cast<unsigned short*>(&h);
}
DI float bf2f(unsigned short u) {
    union { unsigned u; float f; } c; c.u = ((unsigned)u) << 16; return c.f;
}

// async global->LDS, 16B per lane; LDS dest is wave-uniform base + lane*16
DI void async16(unsigned short* lds, const unsigned short* g) {
    __builtin_amdgcn_global_load_lds(
        (const __attribute__((address_space(1))) void*)g,
        (__attribute__((address_space(3))) void*)lds,
        16, 0, 0);
}

template <typename T> DI T cvt_out(float v);
template <> DI float cvt_out<float>(float v) { return v; }
template <> DI unsigned short cvt_out<unsigned short>(float v) { return f2bf(v); }

DI float ldf(const float* p) { return *p; }
DI float ldf(const unsigned short* p) { return bf2f(*p); }

// ---------------------------------------------------------------------------
// GEMM: C[M][N] = A[M][K] @ B[K][N] + bias, with Bt = B^T given as [N][K].
// 128x128 tile, BK=32, 256 threads = 4 waves, each wave 64x64 via 4x4 MFMA
// 16x16x32 bf16. m97 structure: global_load_lds(16B) staging + 2 barriers.
// Fragment layouts (verified, guide section 3):
//   A: lane holds A[m = lane&15][k = (lane>>4)*8 + j]
//   B: lane holds B[k = (lane>>4)*8 + j][n = lane&15]   -> read from Bt[n][k]
//   D: lane,reg r -> row = (lane>>4)*4 + r, col = lane&15
// ---------------------------------------------------------------------------
template <typename OutT, bool RELU>
__global__ __launch_bounds__(256)
void gemm_bt_kernel(const unsigned short* __restrict__ A,   // [M][K] bf16
                    const unsigned short* __restrict__ Bt,  // [N][K] bf16
                    const float* __restrict__ bias,         // [N]
                    OutT* __restrict__ C,                   // [M][N]
                    int M, int N, int K)
{
    constexpr int BM = 128, BN = 128, BK = 32;
    __shared__ unsigned short As[BM * BK];  // [m][k], k contiguous
    __shared__ unsigned short Bs[BN * BK];  // [n][k], k contiguous

    const int tid  = threadIdx.x;
    const int wave = tid >> 6;
    const int lane = tid & 63;
    const int quad = lane >> 4;
    const int l16  = lane & 15;

    const int m0 = blockIdx.y * BM;
    const int n0 = blockIdx.x * BN;
    const int wm = (wave >> 1) * 64;   // wave's m-offset in tile
    const int wn = (wave & 1) * 64;    // wave's n-offset in tile

    floatx4 acc[4][4];
    const floatx4 zero = {0.f, 0.f, 0.f, 0.f};
#pragma unroll
    for (int i = 0; i < 4; i++)
#pragma unroll
        for (int j = 0; j < 4; j++) acc[i][j] = zero;

    // Staging: tile = 8192B = 8 chunks of 1024B (64 lanes x 16B).
    // Wave w stages chunks 2w, 2w+1 of both A and B.
    // chunk c: element e = c*512 + lane*8 -> row = e/32 = c*16 + lane/4,
    //          k = (lane&3)*8
    const int rA = lane >> 2;
    const int kA = (lane & 3) * 8;
    const unsigned short* aS0 = A  + (size_t)(m0 + wave * 32 + rA) * K + kA;
    const unsigned short* aS1 = aS0 + (size_t)16 * K;
    const unsigned short* bS0 = Bt + (size_t)(n0 + wave * 32 + rA) * K + kA;
    const unsigned short* bS1 = bS0 + (size_t)16 * K;
    unsigned short* aD0 = &As[wave * 1024];        // wave-uniform LDS bases
    unsigned short* aD1 = &As[wave * 1024 + 512];
    unsigned short* bD0 = &Bs[wave * 1024];
    unsigned short* bD1 = &Bs[wave * 1024 + 512];

    for (int kt = 0; kt < K; kt += BK) {
        __syncthreads();                 // prev iter's ds_reads done
        async16(aD0, aS0 + kt);
        async16(aD1, aS1 + kt);
        async16(bD0, bS0 + kt);
        async16(bD1, bS1 + kt);
        __syncthreads();                 // compiler drains vmcnt before barrier

        bf16x8 af[4], bfr[4];
#pragma unroll
        for (int i = 0; i < 4; i++)
            af[i] = *reinterpret_cast<const bf16x8*>(
                &As[(wm + i * 16 + l16) * BK + quad * 8]);
#pragma unroll
        for (int j = 0; j < 4; j++)
            bfr[j] = *reinterpret_cast<const bf16x8*>(
                &Bs[(wn + j * 16 + l16) * BK + quad * 8]);
#pragma unroll
        for (int i = 0; i < 4; i++)
#pragma unroll
            for (int j = 0; j < 4; j++)
                acc[i][j] = __builtin_amdgcn_mfma_f32_16x16x32_bf16(
                    af[i], bfr[j], acc[i][j], 0, 0, 0);
    }

    // Epilogue
#pragma unroll
    for (int j = 0; j < 4; j++) {
        const int col = n0 + wn + j * 16 + l16;
        const float bv = bias[col];
#pragma unroll
        for (int i = 0; i < 4; i++) {
            const int rbase = m0 + wm + i * 16 + quad * 4;
#pragma unroll
            for (int r = 0; r < 4; r++) {
                float v = acc[i][j][r] + bv;
                if (RELU) v = fmaxf(v, 0.f);
                C[(size_t)(rbase + r) * N + col] = cvt_out<OutT>(v);
            }
        }
    }
}

// ---------------------------------------------------------------------------
// cast fp32 -> bf16, 4 elems/thread
__global__ void cast_f32_to_bf16(const float* __restrict__ src,
                                 unsigned short* __restrict__ dst, int n4) {
    int i = blockIdx.x * blockDim.x + threadIdx.x;
    if (i < n4) {
        float4 v = reinterpret_cast<const float4*>(src)[i];
        ushort4 o = { f2bf(v.x), f2bf(v.y), f2bf(v.z), f2bf(v.w) };
        reinterpret_cast<ushort4*>(dst)[i] = o;
    }
}

// W[k][n] fp32 (1024x1024) -> Wt[n][k] bf16
__global__ void transpose_cast_w(const float* __restrict__ W,
                                 unsigned short* __restrict__ Wt) {
    __shared__ float tile[32][33];
    const int n0 = blockIdx.x * 32, k0 = blockIdx.y * 32;
    const int tx = threadIdx.x, ty = threadIdx.y;  // 32 x 8
#pragma unroll
    for (int i = 0; i < 32; i += 8)
        tile[ty + i][tx] = W[(size_t)(k0 + ty + i) * 1024 + n0 + tx];
    __syncthreads();
#pragma unroll
    for (int i = 0; i < 32; i += 8)
        Wt[(size_t)(n0 + ty + i) * 1024 + k0 + tx] = f2bf(tile[tx][ty + i]);
}

__global__ void concat_bias(const float* __restrict__ bq,
                            const float* __restrict__ bk,
                            const float* __restrict__ bv,
                            float* __restrict__ dst) {
    int i = blockIdx.x * blockDim.x + threadIdx.x;  // 3072
    const float* s = (i < 1024) ? bq : ((i < 2048) ? bk : bv);
    dst[i] = s[i & 1023];
}

// ---------------------------------------------------------------------------
// Per-token attention over 8 heads. qkv row: [q(1024) | k(1024) | v(1024)].
// scores[h][t] = q[h].k[t]/sqrt(128); softmax over t; out[h] = sum_t w*v[t].
// One block (256 thr) per token. Writes attn weights (fp32) + out (bf16).
template <typename QkvT>
__global__ __launch_bounds__(256)
void attention_kernel(const QkvT* __restrict__ qkv,           // [M][3072]
                      unsigned short* __restrict__ out_bf,    // [M][1024]
                      float* __restrict__ attn_w)             // [M][64]
{
    __shared__ float sq[1024], sk[1024], sv[1024], sw[64];
    const int m = blockIdx.x;
    const int tid = threadIdx.x;
    const QkvT* row = qkv + (size_t)m * 3072;
#pragma unroll
    for (int i = 0; i < 4; i++) {
        int idx = tid + i * 256;
        sq[idx] = ldf(row + idx);
        sk[idx] = ldf(row + 1024 + idx);
        sv[idx] = ldf(row + 2048 + idx);
    }
    __syncthreads();
    if (tid < 64) {                      // wave 0: one (h,t) pair per lane
        const int h = tid >> 3, t = tid & 7;
        const float4* q4 = reinterpret_cast<const float4*>(&sq[h * 128]);
        const float4* k4 = reinterpret_cast<const float4*>(&sk[t * 128]);
        float dot = 0.f;
#pragma unroll
        for (int d = 0; d < 32; d++) {
            float4 a = q4[d], b = k4[d];
            dot += a.x * b.x + a.y * b.y + a.z * b.z + a.w * b.w;
        }
        float score = dot * 0.08838834764831843f;  // 1/sqrt(128)
        float mx = score;
#pragma unroll
        for (int o = 1; o < 8; o <<= 1) mx = fmaxf(mx, __shfl_xor(mx, o, 8));
        float e = __expf(score - mx);
        float sum = e;
#pragma unroll
        for (int o = 1; o < 8; o <<= 1) sum += __shfl_xor(sum, o, 8);
        float w = e / sum;
        sw[tid] = w;
        attn_w[(size_t)m * 64 + tid] = w;
    }
    __syncthreads();
#pragma unroll
    for (int i = 0; i < 4; i++) {
        int j = tid + i * 256;
        int h = j >> 7, d = j & 127;
        float acc = 0.f;
#pragma unroll
        for (int t = 0; t < 8; t++) acc += sw[h * 8 + t] * sv[t * 128 + d];
        out_bf[(size_t)m * 1024 + j] = f2bf(acc);
    }
}

// ---------------------------------------------------------------------------
extern "C" void kernel_launch(void* const* d_in, const int* in_sizes, int n_in,
                              void* d_out, int out_size, void* d_ws, size_t ws_size,
                              hipStream_t stream) {
    const float* x  = (const float*)d_in[0];
    const float* Wq = (const float*)d_in[1];
    const float* bq = (const float*)d_in[2];
    const float* Wk = (const float*)d_in[3];
    const float* bk = (const float*)d_in[4];
    const float* Wv = (const float*)d_in[5];
    const float* bv = (const float*)d_in[6];
    const float* W1 = (const float*)d_in[7];
    const float* b1 = (const float*)d_in[8];
    const float* W2 = (const float*)d_in[9];
    const float* b2 = (const float*)d_in[10];

    constexpr int D = 1024;
    constexpr int M = 4 * 4096;              // 16384 tokens
    constexpr size_t XN = (size_t)M * D;     // 16,777,216

    float* ff_out   = (float*)d_out;         // [M][1024]
    float* attn_out = (float*)d_out + XN;    // [M][64]

    char* ws = (char*)d_ws;
    size_t off = 0;
    auto alloc = [&](size_t bytes) -> char* {
        char* p = ws + off;
        off += (bytes + 255) & ~(size_t)255;
        return p;
    };
    unsigned short* Xbf   = (unsigned short*)alloc(XN * 2);
    unsigned short* Wtqkv = (unsigned short*)alloc((size_t)3 * D * D * 2);
    unsigned short* Wt1   = (unsigned short*)alloc((size_t)D * D * 2);
    unsigned short* Wt2   = (unsigned short*)alloc((size_t)D * D * 2);
    float*          bqkv  = (float*)alloc(3 * D * 4);
    unsigned short* outbf = (unsigned short*)alloc(XN * 2);
    unsigned short* hbf   = (unsigned short*)alloc(XN * 2);
    const bool fp32qkv = (off + (size_t)M * 3 * D * 4 + 256) <= ws_size;

    // prep: casts + transposes (tiny)
    cast_f32_to_bf16<<<(int)(XN / 4 / 256), 256, 0, stream>>>(x, Xbf, (int)(XN / 4));
    dim3 tb(32, 8), tg(32, 32);
    transpose_cast_w<<<tg, tb, 0, stream>>>(Wq, Wtqkv);
    transpose_cast_w<<<tg, tb, 0, stream>>>(Wk, Wtqkv + (size_t)D * D);
    transpose_cast_w<<<tg, tb, 0, stream>>>(Wv, Wtqkv + (size_t)2 * D * D);
    transpose_cast_w<<<tg, tb, 0, stream>>>(W1, Wt1);
    transpose_cast_w<<<tg, tb, 0, stream>>>(W2, Wt2);
    concat_bias<<<12, 256, 0, stream>>>(bq, bk, bv, bqkv);

    // QKV projection + attention
    if (fp32qkv) {
        float* qkv = (float*)alloc((size_t)M * 3 * D * 4);
        gemm_bt_kernel<float, false><<<dim3(3 * D / 128, M / 128), 256, 0, stream>>>(
            Xbf, Wtqkv, bqkv, qkv, M, 3 * D, D);
        attention_kernel<float><<<M, 256, 0, stream>>>(qkv, outbf, attn_out);
    } else {
        unsigned short* qkv = (unsigned short*)alloc((size_t)M * 3 * D * 2);
        gemm_bt_kernel<unsigned short, false><<<dim3(3 * D / 128, M / 128), 256, 0, stream>>>(
            Xbf, Wtqkv, bqkv, qkv, M, 3 * D, D);
        attention_kernel<unsigned short><<<M, 256, 0, stream>>>(qkv, outbf, attn_out);
    }

    // FFN
    gemm_bt_kernel<unsigned short, true><<<dim3(D / 128, M / 128), 256, 0, stream>>>(
        outbf, Wt1, b1, hbf, M, D, D);
    gemm_bt_kernel<float, false><<<dim3(D / 128, M / 128), 256, 0, stream>>>(
        hbf, Wt2, b2, ff_out, M, D, D);
}

// Round 2
// 467.723 us; speedup vs baseline: 1.0016x; 1.0016x over previous
//
#include <hip/hip_runtime.h>
#include <hip/hip_bf16.h>

// TransformerEncoderLayer: B=4,S=4096,D=1024, 8 heads x 128.
//   cast x -> bf16; transpose+cast W* -> Wt[n][k] bf16 (one merged kernel)
//   GEMM1: qkv = x @ [Wq|Wk|Wv] + b      (bf16 out)
//   attention: per-token 8x8 softmax     (vectorized; attn_weights -> d_out tail)
//   GEMM2: h = relu(out @ W1 + b1)       (bf16 out)
//   GEMM3: ff = h @ W2 + b2              (fp32 -> d_out head)
//
// R2 changes vs R1:
//  - GEMM LDS XOR swizzle (q' = q ^ ((row>>1)&3)): kills the 8-way phase
//    conflicts on ds_read_b128 (SQ_LDS_BANK_CONFLICT 1.26e7 -> ~0) while
//    keeping global_load_lds 4-lane/64B coalescing on the staging side.
//  - attention kernel: uint4 (8xbf16) vector loads, float4 PV, ushort4 stores.
//  - 5 weight transposes merged into one z-indexed launch.

#define DI __device__ __forceinline__

typedef __bf16 bf16raw;
typedef bf16raw bf16x8 __attribute__((ext_vector_type(8)));
typedef float floatx4 __attribute__((ext_vector_type(4)));

DI unsigned short f2bf(float f) {
    __hip_bfloat16 h = __float2bfloat16(f);  // RNE
    return *reinterpret_cast<unsigned short*>(&h);
}
DI float bf2f(unsigned short u) {
    union { unsigned u; float f; } c; c.u = ((unsigned)u) << 16; return c.f;
}

// async global->LDS, 16B per lane; LDS dest is wave-uniform base + lane*16
DI void async16(unsigned short* lds, const unsigned short* g) {
    __builtin_amdgcn_global_load_lds(
        (const __attribute__((address_space(1))) void*)g,
        (__attribute__((address_space(3))) void*)lds,
        16, 0, 0);
}

template <typename T> DI T cvt_out(float v);
template <> DI float cvt_out<float>(float v) { return v; }
template <> DI unsigned short cvt_out<unsigned short>(float v) { return f2bf(v); }

// ---------------------------------------------------------------------------
// GEMM: C[M][N] = A[M][K] @ B[K][N] + bias, with Bt = B^T given as [N][K].
// 128x128 tile, BK=32, 256 threads = 4 waves, each wave 64x64 via 4x4 MFMA
// 16x16x32 bf16. global_load_lds(16B) staging + 2 barriers (m97 structure).
//
// LDS layout: row-major [row][BK] with XOR swizzle on the 16B chunk slot:
//   phys_chunk(row, q) = row*4 + (q ^ ((row>>1)&3)),  q = k-oct (8 elems).
// Staging lane l (chunk l of a 1024B async): row = base + l>>2, and it must
// fetch global k-oct q = (l&3) ^ ((l>>3)&3) so that phys slot l&3 holds it.
// Fragment read replaces `quad` with quad ^ ((l16>>1)&3). Net: ds_read_b128
// hits every bank-group with exactly 2 lanes per 16-lane phase (= free),
// staging keeps 4-lane/64B global contiguity.
// ---------------------------------------------------------------------------
template <typename OutT, bool RELU>
__global__ __launch_bounds__(256)
void gemm_bt_kernel(const unsigned short* __restrict__ A,   // [M][K] bf16
                    const unsigned short* __restrict__ Bt,  // [N][K] bf16
                    const float* __restrict__ bias,         // [N]
                    OutT* __restrict__ C,                   // [M][N]
                    int M, int N, int K)
{
    constexpr int BM = 128, BN = 128, BK = 32;
    __shared__ unsigned short As[BM * BK];
    __shared__ unsigned short Bs[BN * BK];

    const int tid  = threadIdx.x;
    const int wave = tid >> 6;
    const int lane = tid & 63;
    const int quad = lane >> 4;
    const int l16  = lane & 15;
    const int quadA = quad ^ ((l16 >> 1) & 3);   // swizzled k-oct slot

    const int m0 = blockIdx.y * BM;
    const int n0 = blockIdx.x * BN;
    const int wm = (wave >> 1) * 64;
    const int wn = (wave & 1) * 64;

    floatx4 acc[4][4];
    const floatx4 zero = {0.f, 0.f, 0.f, 0.f};
#pragma unroll
    for (int i = 0; i < 4; i++)
#pragma unroll
        for (int j = 0; j < 4; j++) acc[i][j] = zero;

    // Staging: tile = 8KB = 8 chunks of 1024B. Wave w stages chunks 2w,2w+1.
    const int rA = lane >> 2;
    const int kA = (((lane & 3) ^ ((lane >> 3) & 3)) * 8);  // swizzled k-oct
    const unsigned short* aS0 = A  + (size_t)(m0 + wave * 32 + rA) * K + kA;
    const unsigned short* aS1 = aS0 + (size_t)16 * K;
    const unsigned short* bS0 = Bt + (size_t)(n0 + wave * 32 + rA) * K + kA;
    const unsigned short* bS1 = bS0 + (size_t)16 * K;
    unsigned short* aD0 = &As[wave * 1024];        // wave-uniform LDS bases
    unsigned short* aD1 = &As[wave * 1024 + 512];
    unsigned short* bD0 = &Bs[wave * 1024];
    unsigned short* bD1 = &Bs[wave * 1024 + 512];

    for (int kt = 0; kt < K; kt += BK) {
        __syncthreads();                 // prev iter's ds_reads done
        async16(aD0, aS0 + kt);
        async16(aD1, aS1 + kt);
        async16(bD0, bS0 + kt);
        async16(bD1, bS1 + kt);
        __syncthreads();                 // drains vmcnt before barrier

        bf16x8 af[4], bfr[4];
#pragma unroll
        for (int i = 0; i < 4; i++)
            af[i] = *reinterpret_cast<const bf16x8*>(
                &As[(wm + i * 16 + l16) * BK + quadA * 8]);
#pragma unroll
        for (int j = 0; j < 4; j++)
            bfr[j] = *reinterpret_cast<const bf16x8*>(
                &Bs[(wn + j * 16 + l16) * BK + quadA * 8]);
#pragma unroll
        for (int i = 0; i < 4; i++)
#pragma unroll
            for (int j = 0; j < 4; j++)
                acc[i][j] = __builtin_amdgcn_mfma_f32_16x16x32_bf16(
                    af[i], bfr[j], acc[i][j], 0, 0, 0);
    }

    // Epilogue (D layout: row = quad*4 + r, col = l16)
#pragma unroll
    for (int j = 0; j < 4; j++) {
        const int col = n0 + wn + j * 16 + l16;
        const float bv = bias[col];
#pragma unroll
        for (int i = 0; i < 4; i++) {
            const int rbase = m0 + wm + i * 16 + quad * 4;
#pragma unroll
            for (int r = 0; r < 4; r++) {
                float v = acc[i][j][r] + bv;
                if (RELU) v = fmaxf(v, 0.f);
                C[(size_t)(rbase + r) * N + col] = cvt_out<OutT>(v);
            }
        }
    }
}

// ---------------------------------------------------------------------------
// cast fp32 -> bf16, 4 elems/thread
__global__ void cast_f32_to_bf16(const float* __restrict__ src,
                                 unsigned short* __restrict__ dst, int n4) {
    int i = blockIdx.x * blockDim.x + threadIdx.x;
    if (i < n4) {
        float4 v = reinterpret_cast<const float4*>(src)[i];
        ushort4 o = { f2bf(v.x), f2bf(v.y), f2bf(v.z), f2bf(v.w) };
        reinterpret_cast<ushort4*>(dst)[i] = o;
    }
}

// 5x W[k][n] fp32 (1024x1024) -> Wt[n][k] bf16, z-indexed
struct WPack {
    const float* src[5];
    unsigned short* dst[5];
};
__global__ void transpose_cast_all(WPack p) {
    __shared__ float tile[32][33];
    const float* W = p.src[blockIdx.z];
    unsigned short* Wt = p.dst[blockIdx.z];
    const int n0 = blockIdx.x * 32, k0 = blockIdx.y * 32;
    const int tx = threadIdx.x, ty = threadIdx.y;  // 32 x 8
#pragma unroll
    for (int i = 0; i < 32; i += 8)
        tile[ty + i][tx] = W[(size_t)(k0 + ty + i) * 1024 + n0 + tx];
    __syncthreads();
#pragma unroll
    for (int i = 0; i < 32; i += 8)
        Wt[(size_t)(n0 + ty + i) * 1024 + k0 + tx] = f2bf(tile[tx][ty + i]);
}

__global__ void concat_bias(const float* __restrict__ bq,
                            const float* __restrict__ bk,
                            const float* __restrict__ bv,
                            float* __restrict__ dst) {
    int i = blockIdx.x * blockDim.x + threadIdx.x;  // 3072
    const float* s = (i < 1024) ? bq : ((i < 2048) ? bk : bv);
    dst[i] = s[i & 1023];
}

// ---------------------------------------------------------------------------
// Per-token attention over 8 heads. qkv row: [q(1024) | k(1024) | v(1024)]
// bf16. One block (256 thr) per token. Vectorized: uint4 loads (8 bf16),
// float4 PV, ushort4 stores.
__global__ __launch_bounds__(256)
void attention_kernel(const unsigned short* __restrict__ qkv,  // [M][3072]
                      unsigned short* __restrict__ out_bf,     // [M][1024]
                      float* __restrict__ attn_w)              // [M][64]
{
    __shared__ float s[3072];    // [q | k | v] as fp32
    __shared__ float sw[64];
    const int m = blockIdx.x;
    const int tid = threadIdx.x;
    const uint4* row = reinterpret_cast<const uint4*>(qkv + (size_t)m * 3072);

    // 384 chunks of 16B; unpack 8 bf16 -> 8 fp32 into LDS
    for (int c = tid; c < 384; c += 256) {
        uint4 u = row[c];
        unsigned v[4] = { u.x, u.y, u.z, u.w };
        float* dst = &s[c * 8];
#pragma unroll
        for (int i = 0; i < 4; i++) {
            union { unsigned u; float f; } lo, hi;
            lo.u = v[i] << 16;
            hi.u = v[i] & 0xffff0000u;
            dst[i * 2]     = lo.f;
            dst[i * 2 + 1] = hi.f;
        }
    }
    __syncthreads();

    if (tid < 64) {                      // wave 0: one (h,t) pair per lane
        const int h = tid >> 3, t = tid & 7;
        const float4* q4 = reinterpret_cast<const float4*>(&s[h * 128]);
        const float4* k4 = reinterpret_cast<const float4*>(&s[1024 + t * 128]);
        float dot = 0.f;
#pragma unroll
        for (int d = 0; d < 32; d++) {
            float4 a = q4[d], b = k4[d];
            dot += a.x * b.x + a.y * b.y + a.z * b.z + a.w * b.w;
        }
        float score = dot * 0.08838834764831843f;  // 1/sqrt(128)
        float mx = score;
#pragma unroll
        for (int o = 1; o < 8; o <<= 1) mx = fmaxf(mx, __shfl_xor(mx, o, 8));
        float e = __expf(score - mx);
        float sum = e;
#pragma unroll
        for (int o = 1; o < 8; o <<= 1) sum += __shfl_xor(sum, o, 8);
        float w = e / sum;
        sw[tid] = w;
        attn_w[(size_t)m * 64 + tid] = w;
    }
    __syncthreads();

    // PV: thread t -> 4 consecutive outputs j = 4t .. 4t+3 (same head)
    {
        const int h  = tid >> 5;
        const int d0 = (tid & 31) * 4;
        float4 acc = { 0.f, 0.f, 0.f, 0.f };
#pragma unroll
        for (int t = 0; t < 8; t++) {
            const float w = sw[h * 8 + t];
            const float4 vv = *reinterpret_cast<const float4*>(&s[2048 + t * 128 + d0]);
            acc.x += w * vv.x; acc.y += w * vv.y;
            acc.z += w * vv.z; acc.w += w * vv.w;
        }
        ushort4 o = { f2bf(acc.x), f2bf(acc.y), f2bf(acc.z), f2bf(acc.w) };
        reinterpret_cast<ushort4*>(out_bf + (size_t)m * 1024)[tid] = o;
    }
}

// ---------------------------------------------------------------------------
extern "C" void kernel_launch(void* const* d_in, const int* in_sizes, int n_in,
                              void* d_out, int out_size, void* d_ws, size_t ws_size,
                              hipStream_t stream) {
    const float* x  = (const float*)d_in[0];
    const float* Wq = (const float*)d_in[1];
    const float* bq = (const float*)d_in[2];
    const float* Wk = (const float*)d_in[3];
    const float* bk = (const float*)d_in[4];
    const float* Wv = (const float*)d_in[5];
    const float* bv = (const float*)d_in[6];
    const float* W1 = (const float*)d_in[7];
    const float* b1 = (const float*)d_in[8];
    const float* W2 = (const float*)d_in[9];
    const float* b2 = (const float*)d_in[10];

    constexpr int D = 1024;
    constexpr int M = 4 * 4096;              // 16384 tokens
    constexpr size_t XN = (size_t)M * D;

    float* ff_out   = (float*)d_out;         // [M][1024]
    float* attn_out = (float*)d_out + XN;    // [M][64]

    char* ws = (char*)d_ws;
    size_t off = 0;
    auto alloc = [&](size_t bytes) -> char* {
        char* p = ws + off;
        off += (bytes + 255) & ~(size_t)255;
        return p;
    };
    unsigned short* Xbf   = (unsigned short*)alloc(XN * 2);
    unsigned short* Wtqkv = (unsigned short*)alloc((size_t)3 * D * D * 2);
    unsigned short* Wt1   = (unsigned short*)alloc((size_t)D * D * 2);
    unsigned short* Wt2   = (unsigned short*)alloc((size_t)D * D * 2);
    float*          bqkv  = (float*)alloc(3 * D * 4);
    unsigned short* outbf = (unsigned short*)alloc(XN * 2);
    unsigned short* hbf   = (unsigned short*)alloc(XN * 2);
    unsigned short* qkv   = (unsigned short*)alloc((size_t)M * 3 * D * 2);

    // prep
    cast_f32_to_bf16<<<(int)(XN / 4 / 256), 256, 0, stream>>>(x, Xbf, (int)(XN / 4));
    WPack p;
    p.src[0] = Wq; p.dst[0] = Wtqkv;
    p.src[1] = Wk; p.dst[1] = Wtqkv + (size_t)D * D;
    p.src[2] = Wv; p.dst[2] = Wtqkv + (size_t)2 * D * D;
    p.src[3] = W1; p.dst[3] = Wt1;
    p.src[4] = W2; p.dst[4] = Wt2;
    transpose_cast_all<<<dim3(32, 32, 5), dim3(32, 8), 0, stream>>>(p);
    concat_bias<<<12, 256, 0, stream>>>(bq, bk, bv, bqkv);

    // QKV projection + attention
    gemm_bt_kernel<unsigned short, false><<<dim3(3 * D / 128, M / 128), 256, 0, stream>>>(
        Xbf, Wtqkv, bqkv, qkv, M, 3 * D, D);
    attention_kernel<<<M, 256, 0, stream>>>(qkv, outbf, attn_out);

    // FFN
    gemm_bt_kernel<unsigned short, true><<<dim3(D / 128, M / 128), 256, 0, stream>>>(
        outbf, Wt1, b1, hbf, M, D, D);
    gemm_bt_kernel<float, false><<<dim3(D / 128, M / 128), 256, 0, stream>>>(
        hbf, Wt2, b2, ff_out, M, D, D);
}

// Round 4
// 418.588 us; speedup vs baseline: 1.1191x; 1.1174x over previous
//
#include <hip/hip_runtime.h>
#include <hip/hip_bf16.h>

// TransformerEncoderLayer: B=4,S=4096,D=1024, 8 heads x 128.
//   cast x -> bf16; transpose+cast W* -> Wt[n][k] bf16 (one merged kernel)
//   GEMM1: qkv = x @ [Wq|Wk|Wv] + b      (bf16 out)
//   attention: per-token 8x8 softmax     (1 wave/token; attn_w -> d_out tail)
//   GEMM2: h = relu(out @ W1 + b1)       (bf16 out)
//   GEMM3: ff = h @ W2 + b2              (fp32 -> d_out head)
//
// R4 = R3 with the attention PV indexing bug fixed:
//   PV must index v as [t][d] with d = within-head dim = (lane&7)*16,
//   NOT the absolute output column lane*16 (which read OOB LDS for heads
//   h>=1 -> stale-bit NaNs that cascaded through the FFN).

#define DI __device__ __forceinline__

typedef __bf16 bf16raw;
typedef bf16raw bf16x8 __attribute__((ext_vector_type(8)));
typedef float floatx4 __attribute__((ext_vector_type(4)));

DI unsigned short f2bf(float f) {
    __hip_bfloat16 h = __float2bfloat16(f);  // RNE
    return *reinterpret_cast<unsigned short*>(&h);
}

// async global->LDS, 16B per lane; LDS dest is wave-uniform base + lane*16
DI void async16(unsigned short* lds, const unsigned short* g) {
    __builtin_amdgcn_global_load_lds(
        (const __attribute__((address_space(1))) void*)g,
        (__attribute__((address_space(3))) void*)lds,
        16, 0, 0);
}

template <typename T> DI T cvt_out(float v);
template <> DI float cvt_out<float>(float v) { return v; }
template <> DI unsigned short cvt_out<unsigned short>(float v) { return f2bf(v); }

// ---------------------------------------------------------------------------
// GEMM: C[M][N] = A[M][K] @ B[K][N] + bias, Bt = B^T given as [N][K] bf16.
// 128x128 tile, BK=64, 256 threads = 4 waves, each wave 64x64 via 4x4 MFMA
// 16x16x32 bf16, 2 k-steps per tile. global_load_lds(16B) staging.
//
// LDS layout: [row][64] (128 B rows), 16B-chunk slot swizzled:
//   phys_slot(row, oct) = oct ^ (row & 7),  oct = k-oct (8 elems) 0..7.
// Staging chunk g (1024B, 64 lanes): row = g*8 + (lane>>3), phys slot
// lane&7 holds global oct ((lane&7) ^ (lane>>3)). 8-lane groups cover a
// full contiguous 128B row (permuted within-row) -> coalesced.
// Fragment read: row&7 = l16&7, oct = s*4 + quad ->
//   slot = (s*4 + quad) ^ (l16 & 7): per 16-lane phase all 8 bank-groups
//   x 2 lanes = conflict-free.
// ---------------------------------------------------------------------------
template <typename OutT, bool RELU>
__global__ __launch_bounds__(256)
void gemm_bt_kernel(const unsigned short* __restrict__ A,   // [M][K] bf16
                    const unsigned short* __restrict__ Bt,  // [N][K] bf16
                    const float* __restrict__ bias,         // [N]
                    OutT* __restrict__ C,                   // [M][N]
                    int M, int N, int K)
{
    constexpr int BM = 128, BN = 128, BK = 64;
    __shared__ unsigned short As[BM * BK];   // 16 KB
    __shared__ unsigned short Bs[BN * BK];   // 16 KB

    const int tid  = threadIdx.x;
    const int wave = tid >> 6;
    const int lane = tid & 63;
    const int quad = lane >> 4;
    const int l16  = lane & 15;
    const int sw7  = l16 & 7;                // fragment-read swizzle key

    const int m0 = blockIdx.y * BM;
    const int n0 = blockIdx.x * BN;
    const int wm = (wave >> 1) * 64;
    const int wn = (wave & 1) * 64;

    floatx4 acc[4][4];
    const floatx4 zero = {0.f, 0.f, 0.f, 0.f};
#pragma unroll
    for (int i = 0; i < 4; i++)
#pragma unroll
        for (int j = 0; j < 4; j++) acc[i][j] = zero;

    // Staging: each tile = 16 KB = 16 chunks of 1024B. Wave w: chunks 4w..4w+3.
    const int rA = lane >> 3;                               // 0..7
    const int kA = (((lane & 7) ^ rA) * 8);                 // swizzled k-oct
    const unsigned short* aS[4];
    const unsigned short* bS[4];
    unsigned short* aD[4];
    unsigned short* bD[4];
#pragma unroll
    for (int c = 0; c < 4; c++) {
        const int row = wave * 32 + c * 8 + rA;
        aS[c] = A  + (size_t)(m0 + row) * K + kA;
        bS[c] = Bt + (size_t)(n0 + row) * K + kA;
        aD[c] = &As[wave * 2048 + c * 512];   // wave-uniform LDS bases
        bD[c] = &Bs[wave * 2048 + c * 512];
    }

    for (int kt = 0; kt < K; kt += BK) {
        __syncthreads();                 // prev iter's ds_reads done
#pragma unroll
        for (int c = 0; c < 4; c++) {
            async16(aD[c], aS[c] + kt);
            async16(bD[c], bS[c] + kt);
        }
        __syncthreads();                 // drains vmcnt before barrier

#pragma unroll
        for (int s = 0; s < 2; s++) {    // two 32-wide k-steps
            bf16x8 af[4], bfr[4];
            const int slot = ((s * 4 + quad) ^ sw7) * 8;
#pragma unroll
            for (int i = 0; i < 4; i++)
                af[i] = *reinterpret_cast<const bf16x8*>(
                    &As[(wm + i * 16 + l16) * BK + slot]);
#pragma unroll
            for (int j = 0; j < 4; j++)
                bfr[j] = *reinterpret_cast<const bf16x8*>(
                    &Bs[(wn + j * 16 + l16) * BK + slot]);
#pragma unroll
            for (int i = 0; i < 4; i++)
#pragma unroll
                for (int j = 0; j < 4; j++)
                    acc[i][j] = __builtin_amdgcn_mfma_f32_16x16x32_bf16(
                        af[i], bfr[j], acc[i][j], 0, 0, 0);
        }
    }

    // Epilogue (D layout: row = quad*4 + r, col = l16)
#pragma unroll
    for (int j = 0; j < 4; j++) {
        const int col = n0 + wn + j * 16 + l16;
        const float bv = bias[col];
#pragma unroll
        for (int i = 0; i < 4; i++) {
            const int rbase = m0 + wm + i * 16 + quad * 4;
#pragma unroll
            for (int r = 0; r < 4; r++) {
                float v = acc[i][j][r] + bv;
                if (RELU) v = fmaxf(v, 0.f);
                C[(size_t)(rbase + r) * N + col] = cvt_out<OutT>(v);
            }
        }
    }
}

// ---------------------------------------------------------------------------
// cast fp32 -> bf16, 4 elems/thread
__global__ void cast_f32_to_bf16(const float* __restrict__ src,
                                 unsigned short* __restrict__ dst, int n4) {
    int i = blockIdx.x * blockDim.x + threadIdx.x;
    if (i < n4) {
        float4 v = reinterpret_cast<const float4*>(src)[i];
        ushort4 o = { f2bf(v.x), f2bf(v.y), f2bf(v.z), f2bf(v.w) };
        reinterpret_cast<ushort4*>(dst)[i] = o;
    }
}

// 5x W[k][n] fp32 (1024x1024) -> Wt[n][k] bf16, z-indexed
struct WPack {
    const float* src[5];
    unsigned short* dst[5];
};
__global__ void transpose_cast_all(WPack p) {
    __shared__ float tile[32][33];
    const float* W = p.src[blockIdx.z];
    unsigned short* Wt = p.dst[blockIdx.z];
    const int n0 = blockIdx.x * 32, k0 = blockIdx.y * 32;
    const int tx = threadIdx.x, ty = threadIdx.y;  // 32 x 8
#pragma unroll
    for (int i = 0; i < 32; i += 8)
        tile[ty + i][tx] = W[(size_t)(k0 + ty + i) * 1024 + n0 + tx];
    __syncthreads();
#pragma unroll
    for (int i = 0; i < 32; i += 8)
        Wt[(size_t)(n0 + ty + i) * 1024 + k0 + tx] = f2bf(tile[tx][ty + i]);
}

__global__ void concat_bias(const float* __restrict__ bq,
                            const float* __restrict__ bk,
                            const float* __restrict__ bv,
                            float* __restrict__ dst) {
    int i = blockIdx.x * blockDim.x + threadIdx.x;  // 3072
    const float* s = (i < 1024) ? bq : ((i < 2048) ? bk : bv);
    dst[i] = s[i & 1023];
}

// ---------------------------------------------------------------------------
// Per-token attention over 8 heads. qkv row: [q(1024)|k(1024)|v(1024)] bf16.
// 4 tokens per block, ONE WAVE PER TOKEN. bf16 stays bf16 in LDS.
DI float dot8(unsigned a, unsigned b, float acc) {
    union { unsigned u; float f; } al, ah, bl, bh;
    al.u = a << 16; ah.u = a & 0xffff0000u;
    bl.u = b << 16; bh.u = b & 0xffff0000u;
    return acc + al.f * bl.f + ah.f * bh.f;
}

__global__ __launch_bounds__(256)
void attention_kernel(const unsigned short* __restrict__ qkv,  // [M][3072]
                      unsigned short* __restrict__ out_bf,     // [M][1024]
                      float* __restrict__ attn_w)              // [M][64]
{
    __shared__ unsigned short sqkv[4][3072];   // 24 KB
    __shared__ float sw[4][64];
    const int tid  = threadIdx.x;
    const int wave = tid >> 6;
    const int lane = tid & 63;
    const int m    = blockIdx.x * 4 + wave;    // this wave's token

    // Stage own token's qkv row: 384 uint4 chunks / 64 lanes = 6 per lane
    {
        const uint4* src = reinterpret_cast<const uint4*>(qkv + (size_t)m * 3072);
        uint4* dst = reinterpret_cast<uint4*>(&sqkv[wave][0]);
#pragma unroll
        for (int i = 0; i < 6; i++) dst[lane + 64 * i] = src[lane + 64 * i];
    }
    __syncthreads();

    // QK + softmax: lane = h*8 + t
    {
        const int h = lane >> 3, t = lane & 7;
        const uint2* q8 = reinterpret_cast<const uint2*>(&sqkv[wave][h * 128]);
        const uint2* k8 = reinterpret_cast<const uint2*>(&sqkv[wave][1024 + t * 128]);
        float dot = 0.f;
#pragma unroll
        for (int d = 0; d < 32; d++) {
            uint2 a = q8[d], b = k8[d];
            dot = dot8(a.x, b.x, dot);
            dot = dot8(a.y, b.y, dot);
        }
        float score = dot * 0.08838834764831843f;  // 1/sqrt(128)
        float mx = score;
#pragma unroll
        for (int o = 1; o < 8; o <<= 1) mx = fmaxf(mx, __shfl_xor(mx, o, 8));
        float e = __expf(score - mx);
        float sum = e;
#pragma unroll
        for (int o = 1; o < 8; o <<= 1) sum += __shfl_xor(sum, o, 8);
        float w = e / sum;
        sw[wave][lane] = w;
        attn_w[(size_t)m * 64 + lane] = w;     // [m][h][t], coalesced per wave
    }
    __syncthreads();

    // PV: lane owns output cols [lane*16, lane*16+16) = head h = lane>>3,
    // within-head dims d0..d0+15 with d0 = (lane&7)*16.  v is [t][d]!
    {
        const int h  = lane >> 3;
        const int d0 = (lane & 7) * 16;        // within-head dim (THE R3 FIX)
        float acc[16];
#pragma unroll
        for (int i = 0; i < 16; i++) acc[i] = 0.f;
#pragma unroll
        for (int t = 0; t < 8; t++) {
            const float w = sw[wave][h * 8 + t];
            const uint4* v8 = reinterpret_cast<const uint4*>(
                &sqkv[wave][2048 + t * 128 + d0]);
            uint4 v0 = v8[0], v1 = v8[1];
            unsigned vv[8] = { v0.x, v0.y, v0.z, v0.w, v1.x, v1.y, v1.z, v1.w };
#pragma unroll
            for (int i = 0; i < 8; i++) {
                union { unsigned u; float f; } lo, hi;
                lo.u = vv[i] << 16; hi.u = vv[i] & 0xffff0000u;
                acc[i * 2]     += w * lo.f;
                acc[i * 2 + 1] += w * hi.f;
            }
        }
        unsigned o[8];
#pragma unroll
        for (int i = 0; i < 8; i++)
            o[i] = (unsigned)f2bf(acc[i * 2]) | ((unsigned)f2bf(acc[i * 2 + 1]) << 16);
        uint4* dst = reinterpret_cast<uint4*>(out_bf + (size_t)m * 1024 + lane * 16);
        dst[0] = make_uint4(o[0], o[1], o[2], o[3]);
        dst[1] = make_uint4(o[4], o[5], o[6], o[7]);
    }
}

// ---------------------------------------------------------------------------
extern "C" void kernel_launch(void* const* d_in, const int* in_sizes, int n_in,
                              void* d_out, int out_size, void* d_ws, size_t ws_size,
                              hipStream_t stream) {
    const float* x  = (const float*)d_in[0];
    const float* Wq = (const float*)d_in[1];
    const float* bq = (const float*)d_in[2];
    const float* Wk = (const float*)d_in[3];
    const float* bk = (const float*)d_in[4];
    const float* Wv = (const float*)d_in[5];
    const float* bv = (const float*)d_in[6];
    const float* W1 = (const float*)d_in[7];
    const float* b1 = (const float*)d_in[8];
    const float* W2 = (const float*)d_in[9];
    const float* b2 = (const float*)d_in[10];

    constexpr int D = 1024;
    constexpr int M = 4 * 4096;              // 16384 tokens
    constexpr size_t XN = (size_t)M * D;

    float* ff_out   = (float*)d_out;         // [M][1024]
    float* attn_out = (float*)d_out + XN;    // [M][64]

    char* ws = (char*)d_ws;
    size_t off = 0;
    auto alloc = [&](size_t bytes) -> char* {
        char* p = ws + off;
        off += (bytes + 255) & ~(size_t)255;
        return p;
    };
    unsigned short* Xbf   = (unsigned short*)alloc(XN * 2);
    unsigned short* Wtqkv = (unsigned short*)alloc((size_t)3 * D * D * 2);
    unsigned short* Wt1   = (unsigned short*)alloc((size_t)D * D * 2);
    unsigned short* Wt2   = (unsigned short*)alloc((size_t)D * D * 2);
    float*          bqkv  = (float*)alloc(3 * D * 4);
    unsigned short* outbf = (unsigned short*)alloc(XN * 2);
    unsigned short* hbf   = (unsigned short*)alloc(XN * 2);
    unsigned short* qkv   = (unsigned short*)alloc((size_t)M * 3 * D * 2);

    // prep
    cast_f32_to_bf16<<<(int)(XN / 4 / 256), 256, 0, stream>>>(x, Xbf, (int)(XN / 4));
    WPack p;
    p.src[0] = Wq; p.dst[0] = Wtqkv;
    p.src[1] = Wk; p.dst[1] = Wtqkv + (size_t)D * D;
    p.src[2] = Wv; p.dst[2] = Wtqkv + (size_t)2 * D * D;
    p.src[3] = W1; p.dst[3] = Wt1;
    p.src[4] = W2; p.dst[4] = Wt2;
    transpose_cast_all<<<dim3(32, 32, 5), dim3(32, 8), 0, stream>>>(p);
    concat_bias<<<12, 256, 0, stream>>>(bq, bk, bv, bqkv);

    // QKV projection + attention
    gemm_bt_kernel<unsigned short, false><<<dim3(3 * D / 128, M / 128), 256, 0, stream>>>(
        Xbf, Wtqkv, bqkv, qkv, M, 3 * D, D);
    attention_kernel<<<M / 4, 256, 0, stream>>>(qkv, outbf, attn_out);

    // FFN
    gemm_bt_kernel<unsigned short, true><<<dim3(D / 128, M / 128), 256, 0, stream>>>(
        outbf, Wt1, b1, hbf, M, D, D);
    gemm_bt_kernel<float, false><<<dim3(D / 128, M / 128), 256, 0, stream>>>(
        hbf, Wt2, b2, ff_out, M, D, D);
}

// Round 5
// 396.972 us; speedup vs baseline: 1.1801x; 1.0545x over previous
//
#include <hip/hip_runtime.h>
#include <hip/hip_bf16.h>

// TransformerEncoderLayer: B=4,S=4096,D=1024, 8 heads x 128.
//   cast x -> bf16; transpose+cast W* -> Wt[n][k] bf16 (one merged kernel)
//   GEMM1: qkv = x @ [Wq|Wk|Wv] + b      (bf16 out)
//   attention: per-token 8x8 softmax     (1 wave/token; attn_w -> d_out tail)
//   GEMM2: h = relu(out @ W1 + b1)       (bf16 out)
//   GEMM3: ff = h @ W2 + b2              (fp32 -> d_out head)
//
// R5 changes vs R4 (GEMM only; attention/prep kernels unchanged):
//  - K,N,GX compile-time template params: addressing strength-reduces,
//    pointer arrays gone -> fewer VGPRs.
//  - __launch_bounds__(256, 3): cap regs ~170/wave so 64 AGPR acc + VGPRs
//    fit 3 waves/SIMD = 3 blocks/CU (R4 was 156 regs -> 2 blocks, occ 21%).
//  - XCD swizzle (g&7 heuristic): each XCD owns an M-super-strip, walks N
//    fastest -> A-strip (256KB) stays hot in that XCD's L2; staging loads
//    go from L3/HBM latency (~400-900cy) to L2 (~200cy), shrinking the
//    vmcnt(0) barrier drain that MfmaUtil=31% (vs ~67% LDS-bound ceiling)
//    says dominates.

#define DI __device__ __forceinline__

typedef __bf16 bf16raw;
typedef bf16raw bf16x8 __attribute__((ext_vector_type(8)));
typedef float floatx4 __attribute__((ext_vector_type(4)));

DI unsigned short f2bf(float f) {
    __hip_bfloat16 h = __float2bfloat16(f);  // RNE
    return *reinterpret_cast<unsigned short*>(&h);
}

// async global->LDS, 16B per lane; LDS dest is wave-uniform base + lane*16
DI void async16(unsigned short* lds, const unsigned short* g) {
    __builtin_amdgcn_global_load_lds(
        (const __attribute__((address_space(1))) void*)g,
        (__attribute__((address_space(3))) void*)lds,
        16, 0, 0);
}

template <typename T> DI T cvt_out(float v);
template <> DI float cvt_out<float>(float v) { return v; }
template <> DI unsigned short cvt_out<unsigned short>(float v) { return f2bf(v); }

// ---------------------------------------------------------------------------
// GEMM: C[M][N] = A[M][K] @ B[K][N] + bias, Bt = B^T given as [N][K] bf16.
// 128x128 tile, BK=64, 256 threads = 4 waves, each wave 64x64 via 4x4 MFMA
// 16x16x32 bf16, 2 k-steps per tile. global_load_lds(16B) staging.
// LDS swizzle (R4, verified conflict-free): phys_slot(row,oct)=oct^(row&7).
// Grid is (N/128, M/128); bx/by remapped for XCD L2 locality.
// ---------------------------------------------------------------------------
template <int K, int N, int GX, typename OutT, bool RELU>
__global__ __launch_bounds__(256, 3)
void gemm_bt_kernel(const unsigned short* __restrict__ A,   // [M][K] bf16
                    const unsigned short* __restrict__ Bt,  // [N][K] bf16
                    const float* __restrict__ bias,         // [N]
                    OutT* __restrict__ C)                   // [M][N]
{
    constexpr int BM = 128, BN = 128, BK = 64;
    __shared__ unsigned short As[BM * BK];   // 16 KB
    __shared__ unsigned short Bs[BN * BK];   // 16 KB

    const int tid  = threadIdx.x;
    const int wave = tid >> 6;
    const int lane = tid & 63;
    const int quad = lane >> 4;
    const int l16  = lane & 15;
    const int sw7  = l16 & 7;                // fragment-read swizzle key

    // XCD swizzle: linear dispatch id g -> (xcd = g&7 [heuristic], t = g>>3).
    // XCD c owns by in [c*GY/8, (c+1)*GY/8); within it bx walks fastest so
    // the 128-row A strip is reused GX times from this XCD's L2.
    const int g   = blockIdx.x + GX * blockIdx.y;
    const int xcd = g & 7;
    const int t   = g >> 3;
    const int bx  = t % GX;
    const int by  = t / GX + (gridDim.y >> 3) * xcd;

    const int m0 = by * BM;
    const int n0 = bx * BN;
    const int wm = (wave >> 1) * 64;
    const int wn = (wave & 1) * 64;

    floatx4 acc[4][4];
    const floatx4 zero = {0.f, 0.f, 0.f, 0.f};
#pragma unroll
    for (int i = 0; i < 4; i++)
#pragma unroll
        for (int j = 0; j < 4; j++) acc[i][j] = zero;

    // Staging: tile = 16 KB = 16 chunks of 1024B. Wave w: chunks 4w..4w+3.
    const int rA = lane >> 3;                               // 0..7
    const int kA = (((lane & 7) ^ rA) * 8);                 // swizzled k-oct
    const unsigned short* aBase = A  + (size_t)(m0 + wave * 32 + rA) * K + kA;
    const unsigned short* bBase = Bt + (size_t)(n0 + wave * 32 + rA) * K + kA;
    unsigned short* aD = &As[wave * 2048];    // wave-uniform LDS bases
    unsigned short* bD = &Bs[wave * 2048];

    for (int kt = 0; kt < K; kt += BK) {
        __syncthreads();                 // prev iter's ds_reads done
#pragma unroll
        for (int c = 0; c < 4; c++) {
            async16(aD + c * 512, aBase + c * 8 * K + kt);
            async16(bD + c * 512, bBase + c * 8 * K + kt);
        }
        __syncthreads();                 // drains vmcnt before barrier

#pragma unroll
        for (int s = 0; s < 2; s++) {    // two 32-wide k-steps
            bf16x8 af[4], bfr[4];
            const int slot = ((s * 4 + quad) ^ sw7) * 8;
#pragma unroll
            for (int i = 0; i < 4; i++)
                af[i] = *reinterpret_cast<const bf16x8*>(
                    &As[(wm + i * 16 + l16) * BK + slot]);
#pragma unroll
            for (int j = 0; j < 4; j++)
                bfr[j] = *reinterpret_cast<const bf16x8*>(
                    &Bs[(wn + j * 16 + l16) * BK + slot]);
#pragma unroll
            for (int i = 0; i < 4; i++)
#pragma unroll
                for (int j = 0; j < 4; j++)
                    acc[i][j] = __builtin_amdgcn_mfma_f32_16x16x32_bf16(
                        af[i], bfr[j], acc[i][j], 0, 0, 0);
        }
    }

    // Epilogue (D layout: row = quad*4 + r, col = l16)
#pragma unroll
    for (int j = 0; j < 4; j++) {
        const int col = n0 + wn + j * 16 + l16;
        const float bv = bias[col];
#pragma unroll
        for (int i = 0; i < 4; i++) {
            const int rbase = m0 + wm + i * 16 + quad * 4;
#pragma unroll
            for (int r = 0; r < 4; r++) {
                float v = acc[i][j][r] + bv;
                if (RELU) v = fmaxf(v, 0.f);
                C[(size_t)(rbase + r) * N + col] = cvt_out<OutT>(v);
            }
        }
    }
}

// ---------------------------------------------------------------------------
// cast fp32 -> bf16, 4 elems/thread
__global__ void cast_f32_to_bf16(const float* __restrict__ src,
                                 unsigned short* __restrict__ dst, int n4) {
    int i = blockIdx.x * blockDim.x + threadIdx.x;
    if (i < n4) {
        float4 v = reinterpret_cast<const float4*>(src)[i];
        ushort4 o = { f2bf(v.x), f2bf(v.y), f2bf(v.z), f2bf(v.w) };
        reinterpret_cast<ushort4*>(dst)[i] = o;
    }
}

// 5x W[k][n] fp32 (1024x1024) -> Wt[n][k] bf16, z-indexed
struct WPack {
    const float* src[5];
    unsigned short* dst[5];
};
__global__ void transpose_cast_all(WPack p) {
    __shared__ float tile[32][33];
    const float* W = p.src[blockIdx.z];
    unsigned short* Wt = p.dst[blockIdx.z];
    const int n0 = blockIdx.x * 32, k0 = blockIdx.y * 32;
    const int tx = threadIdx.x, ty = threadIdx.y;  // 32 x 8
#pragma unroll
    for (int i = 0; i < 32; i += 8)
        tile[ty + i][tx] = W[(size_t)(k0 + ty + i) * 1024 + n0 + tx];
    __syncthreads();
#pragma unroll
    for (int i = 0; i < 32; i += 8)
        Wt[(size_t)(n0 + ty + i) * 1024 + k0 + tx] = f2bf(tile[tx][ty + i]);
}

__global__ void concat_bias(const float* __restrict__ bq,
                            const float* __restrict__ bk,
                            const float* __restrict__ bv,
                            float* __restrict__ dst) {
    int i = blockIdx.x * blockDim.x + threadIdx.x;  // 3072
    const float* s = (i < 1024) ? bq : ((i < 2048) ? bk : bv);
    dst[i] = s[i & 1023];
}

// ---------------------------------------------------------------------------
// Per-token attention over 8 heads. qkv row: [q(1024)|k(1024)|v(1024)] bf16.
// 4 tokens per block, ONE WAVE PER TOKEN. bf16 stays bf16 in LDS.
DI float dot8(unsigned a, unsigned b, float acc) {
    union { unsigned u; float f; } al, ah, bl, bh;
    al.u = a << 16; ah.u = a & 0xffff0000u;
    bl.u = b << 16; bh.u = b & 0xffff0000u;
    return acc + al.f * bl.f + ah.f * bh.f;
}

__global__ __launch_bounds__(256)
void attention_kernel(const unsigned short* __restrict__ qkv,  // [M][3072]
                      unsigned short* __restrict__ out_bf,     // [M][1024]
                      float* __restrict__ attn_w)              // [M][64]
{
    __shared__ unsigned short sqkv[4][3072];   // 24 KB
    __shared__ float sw[4][64];
    const int tid  = threadIdx.x;
    const int wave = tid >> 6;
    const int lane = tid & 63;
    const int m    = blockIdx.x * 4 + wave;    // this wave's token

    // Stage own token's qkv row: 384 uint4 chunks / 64 lanes = 6 per lane
    {
        const uint4* src = reinterpret_cast<const uint4*>(qkv + (size_t)m * 3072);
        uint4* dst = reinterpret_cast<uint4*>(&sqkv[wave][0]);
#pragma unroll
        for (int i = 0; i < 6; i++) dst[lane + 64 * i] = src[lane + 64 * i];
    }
    __syncthreads();

    // QK + softmax: lane = h*8 + t
    {
        const int h = lane >> 3, t = lane & 7;
        const uint2* q8 = reinterpret_cast<const uint2*>(&sqkv[wave][h * 128]);
        const uint2* k8 = reinterpret_cast<const uint2*>(&sqkv[wave][1024 + t * 128]);
        float dot = 0.f;
#pragma unroll
        for (int d = 0; d < 32; d++) {
            uint2 a = q8[d], b = k8[d];
            dot = dot8(a.x, b.x, dot);
            dot = dot8(a.y, b.y, dot);
        }
        float score = dot * 0.08838834764831843f;  // 1/sqrt(128)
        float mx = score;
#pragma unroll
        for (int o = 1; o < 8; o <<= 1) mx = fmaxf(mx, __shfl_xor(mx, o, 8));
        float e = __expf(score - mx);
        float sum = e;
#pragma unroll
        for (int o = 1; o < 8; o <<= 1) sum += __shfl_xor(sum, o, 8);
        float w = e / sum;
        sw[wave][lane] = w;
        attn_w[(size_t)m * 64 + lane] = w;     // [m][h][t], coalesced per wave
    }
    __syncthreads();

    // PV: lane owns output cols [lane*16, lane*16+16) = head h = lane>>3,
    // within-head dims d0..d0+15 with d0 = (lane&7)*16.  v is [t][d].
    {
        const int h  = lane >> 3;
        const int d0 = (lane & 7) * 16;        // within-head dim
        float acc[16];
#pragma unroll
        for (int i = 0; i < 16; i++) acc[i] = 0.f;
#pragma unroll
        for (int t = 0; t < 8; t++) {
            const float w = sw[wave][h * 8 + t];
            const uint4* v8 = reinterpret_cast<const uint4*>(
                &sqkv[wave][2048 + t * 128 + d0]);
            uint4 v0 = v8[0], v1 = v8[1];
            unsigned vv[8] = { v0.x, v0.y, v0.z, v0.w, v1.x, v1.y, v1.z, v1.w };
#pragma unroll
            for (int i = 0; i < 8; i++) {
                union { unsigned u; float f; } lo, hi;
                lo.u = vv[i] << 16; hi.u = vv[i] & 0xffff0000u;
                acc[i * 2]     += w * lo.f;
                acc[i * 2 + 1] += w * hi.f;
            }
        }
        unsigned o[8];
#pragma unroll
        for (int i = 0; i < 8; i++)
            o[i] = (unsigned)f2bf(acc[i * 2]) | ((unsigned)f2bf(acc[i * 2 + 1]) << 16);
        uint4* dst = reinterpret_cast<uint4*>(out_bf + (size_t)m * 1024 + lane * 16);
        dst[0] = make_uint4(o[0], o[1], o[2], o[3]);
        dst[1] = make_uint4(o[4], o[5], o[6], o[7]);
    }
}

// ---------------------------------------------------------------------------
extern "C" void kernel_launch(void* const* d_in, const int* in_sizes, int n_in,
                              void* d_out, int out_size, void* d_ws, size_t ws_size,
                              hipStream_t stream) {
    const float* x  = (const float*)d_in[0];
    const float* Wq = (const float*)d_in[1];
    const float* bq = (const float*)d_in[2];
    const float* Wk = (const float*)d_in[3];
    const float* bk = (const float*)d_in[4];
    const float* Wv = (const float*)d_in[5];
    const float* bv = (const float*)d_in[6];
    const float* W1 = (const float*)d_in[7];
    const float* b1 = (const float*)d_in[8];
    const float* W2 = (const float*)d_in[9];
    const float* b2 = (const float*)d_in[10];

    constexpr int D = 1024;
    constexpr int M = 4 * 4096;              // 16384 tokens
    constexpr size_t XN = (size_t)M * D;

    float* ff_out   = (float*)d_out;         // [M][1024]
    float* attn_out = (float*)d_out + XN;    // [M][64]

    char* ws = (char*)d_ws;
    size_t off = 0;
    auto alloc = [&](size_t bytes) -> char* {
        char* p = ws + off;
        off += (bytes + 255) & ~(size_t)255;
        return p;
    };
    unsigned short* Xbf   = (unsigned short*)alloc(XN * 2);
    unsigned short* Wtqkv = (unsigned short*)alloc((size_t)3 * D * D * 2);
    unsigned short* Wt1   = (unsigned short*)alloc((size_t)D * D * 2);
    unsigned short* Wt2   = (unsigned short*)alloc((size_t)D * D * 2);
    float*          bqkv  = (float*)alloc(3 * D * 4);
    unsigned short* outbf = (unsigned short*)alloc(XN * 2);
    unsigned short* hbf   = (unsigned short*)alloc(XN * 2);
    unsigned short* qkv   = (unsigned short*)alloc((size_t)M * 3 * D * 2);

    // prep
    cast_f32_to_bf16<<<(int)(XN / 4 / 256), 256, 0, stream>>>(x, Xbf, (int)(XN / 4));
    WPack p;
    p.src[0] = Wq; p.dst[0] = Wtqkv;
    p.src[1] = Wk; p.dst[1] = Wtqkv + (size_t)D * D;
    p.src[2] = Wv; p.dst[2] = Wtqkv + (size_t)2 * D * D;
    p.src[3] = W1; p.dst[3] = Wt1;
    p.src[4] = W2; p.dst[4] = Wt2;
    transpose_cast_all<<<dim3(32, 32, 5), dim3(32, 8), 0, stream>>>(p);
    concat_bias<<<12, 256, 0, stream>>>(bq, bk, bv, bqkv);

    // QKV projection + attention
    gemm_bt_kernel<D, 3 * D, 24, unsigned short, false>
        <<<dim3(24, 128), 256, 0, stream>>>(Xbf, Wtqkv, bqkv, qkv);
    attention_kernel<<<M / 4, 256, 0, stream>>>(qkv, outbf, attn_out);

    // FFN
    gemm_bt_kernel<D, D, 8, unsigned short, true>
        <<<dim3(8, 128), 256, 0, stream>>>(outbf, Wt1, b1, hbf);
    gemm_bt_kernel<D, D, 8, float, false>
        <<<dim3(8, 128), 256, 0, stream>>>(hbf, Wt2, b2, ff_out);
}